// Round 1
// baseline (247.130 us; speedup 1.0000x reference)
//
#include <hip/hip_runtime.h>
#include <math.h>

// Shapes (fixed by the reference):
//   input:  (1, B=16, N=7, HID=256) fp32
//   res_feature: (B, C=256, H=96, W=96) fp32   -- provably unused (softmax shift invariance)
//   node_fea_for_res: (C,1)                    -- provably unused
//   node_fea_for_hidden: (HID,1)
//   weight: (HID, C)
//   out: (B, C, H, W) fp32, each (b,c) plane is a single constant M[b,c].

#define B 16
#define NODES 7
#define HID 256
#define C 256
#define P 9216           // 96*96
#define P4 2304          // P/4

// Kernel 1: one block per batch b, 256 threads.
// Computes M[b,c] = relu( sum_h (sum_n a[b,n]*x[b,n,h]) * W[h,c] )
// with a[b,:] = softmax_n( x[b,n,:] . nfh ).
__global__ __launch_bounds__(256) void compute_M(
    const float* __restrict__ x,    // (B, N, HID)
    const float* __restrict__ nfh,  // (HID)
    const float* __restrict__ W,    // (HID, C)
    float* __restrict__ M) {        // (B, C)
  const int b = blockIdx.x;
  const int t = threadIdx.x;      // 0..255
  const int lane = t & 63;
  const int wave = t >> 6;

  __shared__ float xs[NODES * HID];   // 7 KB
  __shared__ float red[NODES][4];
  __shared__ float a[NODES];
  __shared__ float y[HID];

  // Stage x[b] into LDS (coalesced).
#pragma unroll
  for (int n = 0; n < NODES; ++n)
    xs[n * HID + t] = x[((size_t)b * NODES + n) * HID + t];
  const float f = nfh[t];
  __syncthreads();

  // s_hid[n] = sum_h xs[n][h] * nfh[h]  (block reduction per n)
#pragma unroll
  for (int n = 0; n < NODES; ++n) {
    float v = xs[n * HID + t] * f;
#pragma unroll
    for (int off = 32; off > 0; off >>= 1) v += __shfl_down(v, off, 64);
    if (lane == 0) red[n][wave] = v;
  }
  __syncthreads();

  if (t == 0) {
    float s[NODES];
    float m = -3.0e38f;
#pragma unroll
    for (int n = 0; n < NODES; ++n) {
      s[n] = red[n][0] + red[n][1] + red[n][2] + red[n][3];
      m = fmaxf(m, s[n]);
    }
    float denom = 0.0f;
#pragma unroll
    for (int n = 0; n < NODES; ++n) {
      s[n] = expf(s[n] - m);
      denom += s[n];
    }
    const float inv = 1.0f / denom;
#pragma unroll
    for (int n = 0; n < NODES; ++n) a[n] = s[n] * inv;
  }
  __syncthreads();

  // Combine-first: y[h] = sum_n a[n] * x[b,n,h]
  float yv = 0.0f;
#pragma unroll
  for (int n = 0; n < NODES; ++n) yv = fmaf(a[n], xs[n * HID + t], yv);
  y[t] = yv;
  __syncthreads();

  // M[b,c] = relu( sum_h y[h] * W[h,c] ), c == t (coalesced W reads, L2-resident)
  float acc = 0.0f;
#pragma unroll 8
  for (int h = 0; h < HID; ++h) acc = fmaf(y[h], W[h * C + t], acc);
  M[b * C + t] = fmaxf(acc, 0.0f);
}

// Kernel 2: one block per (b,c) plane; 256 threads write 9 float4 each
// (9216 floats = 2304 float4 per plane). Pure write-BW bound.
__global__ __launch_bounds__(256) void broadcast_fill(
    const float* __restrict__ M,   // (B*C)
    float* __restrict__ out) {     // (B, C, P)
  const int bc = blockIdx.x;       // 0..B*C-1
  const float v = M[bc];
  const float4 v4 = make_float4(v, v, v, v);
  float4* dst = reinterpret_cast<float4*>(out) + (size_t)bc * P4;
  const int t = threadIdx.x;
#pragma unroll
  for (int i = 0; i < 9; ++i) dst[i * 256 + t] = v4;
}

extern "C" void kernel_launch(void* const* d_in, const int* in_sizes, int n_in,
                              void* d_out, int out_size, void* d_ws, size_t ws_size,
                              hipStream_t stream) {
  const float* x   = (const float*)d_in[0];  // (1,B,N,HID)
  // d_in[1] res_feature, d_in[2] node_fea_for_res: unused (softmax shift invariance)
  const float* nfh = (const float*)d_in[3];  // (HID,1)
  const float* W   = (const float*)d_in[4];  // (HID,C)
  float* out = (float*)d_out;
  float* M = (float*)d_ws;                   // B*C floats = 16 KB scratch

  compute_M<<<B, 256, 0, stream>>>(x, nfh, W, M);
  broadcast_fill<<<B * C, 256, 0, stream>>>(M, out);
}

// Round 2
// 235.122 us; speedup vs baseline: 1.0511x; 1.0511x over previous
//
#include <hip/hip_runtime.h>
#include <math.h>

// Shapes (fixed by the reference):
//   input:  (1, B=16, N=7, HID=256) fp32
//   res_feature: (B, C=256, H=96, W=96) fp32   -- provably unused: softmax over
//       nodes of s_res[b,p]+s_hid[b,n] is shift-invariant in the p-term, so
//       attn is pixel-independent and each (b,c) output plane is one constant.
//   node_fea_for_res: (C,1)                    -- provably unused
//   node_fea_for_hidden: (HID,1)
//   weight: (HID, C)
//   out: (B, C, H, W) fp32
//
// Single fused kernel: one block per (b,c) plane. Each block redundantly
// computes the tiny prelude (softmax weights a[b,:], y = a·x[b], M = relu(y·W[:,c]))
// — ~8 KFLOP, hidden under the 36 KB of plane writes — then broadcast-fills
// its plane with float4 stores. Removes the old 16-block latency-bound
// compute_M kernel and one launch gap.

#define B 16
#define NODES 7
#define HID 256
#define C 256
#define P 9216           // 96*96
#define P4 2304          // P/4

__global__ __launch_bounds__(256) void fused_attn_fill(
    const float* __restrict__ x,    // (B, N, HID)
    const float* __restrict__ nfh,  // (HID)
    const float* __restrict__ W,    // (HID, C)
    float* __restrict__ out) {      // (B, C, P)
  const int bc = blockIdx.x;        // 0..B*C-1
  const int b = bc >> 8;            // C == 256
  const int c = bc & (C - 1);
  const int t = threadIdx.x;        // 0..255 ; also the h index this thread owns
  const int lane = t & 63;
  const int wave = t >> 6;

  __shared__ float xs[NODES * HID];   // 7 KB, L2-fed (x is 114 KB total)
  __shared__ float red[NODES][4];
  __shared__ float a[NODES];
  __shared__ float red2[4];
  __shared__ float Msh;

  // Stage x[b] into LDS (coalesced), issue W column load early.
#pragma unroll
  for (int n = 0; n < NODES; ++n)
    xs[n * HID + t] = x[((size_t)b * NODES + n) * HID + t];
  const float f = nfh[t];
  const float wcol = W[t * C + c];   // stride-1KB gather, L2-resident (W=256KB)
  __syncthreads();

  // s_hid[n] = sum_h xs[n][h] * nfh[h]  (per-wave shuffle reduce, 4 partials)
#pragma unroll
  for (int n = 0; n < NODES; ++n) {
    float v = xs[n * HID + t] * f;
#pragma unroll
    for (int off = 32; off > 0; off >>= 1) v += __shfl_down(v, off, 64);
    if (lane == 0) red[n][wave] = v;
  }
  __syncthreads();

  // Softmax over the 7 nodes (serial on t==0 — trivial).
  if (t == 0) {
    float s[NODES];
    float m = -3.0e38f;
#pragma unroll
    for (int n = 0; n < NODES; ++n) {
      s[n] = red[n][0] + red[n][1] + red[n][2] + red[n][3];
      m = fmaxf(m, s[n]);
    }
    float denom = 0.0f;
#pragma unroll
    for (int n = 0; n < NODES; ++n) {
      s[n] = expf(s[n] - m);
      denom += s[n];
    }
    const float inv = 1.0f / denom;
#pragma unroll
    for (int n = 0; n < NODES; ++n) a[n] = s[n] * inv;
  }
  __syncthreads();

  // y[h=t] = sum_n a[n]*x[b,n,t]; partial M contribution = y[t] * W[t,c]
  float yv = 0.0f;
#pragma unroll
  for (int n = 0; n < NODES; ++n) yv = fmaf(a[n], xs[n * HID + t], yv);
  float p = yv * wcol;

  // Block reduce 256 partials -> M[b,c]
#pragma unroll
  for (int off = 32; off > 0; off >>= 1) p += __shfl_down(p, off, 64);
  if (lane == 0) red2[wave] = p;
  __syncthreads();
  if (t == 0) Msh = fmaxf(red2[0] + red2[1] + red2[2] + red2[3], 0.0f);
  __syncthreads();

  // Broadcast-fill this (b,c) plane: 2304 float4 = 9 per thread.
  const float v = Msh;
  const float4 v4 = make_float4(v, v, v, v);
  float4* dst = reinterpret_cast<float4*>(out) + (size_t)bc * P4;
#pragma unroll
  for (int i = 0; i < 9; ++i) dst[i * 256 + t] = v4;
}

extern "C" void kernel_launch(void* const* d_in, const int* in_sizes, int n_in,
                              void* d_out, int out_size, void* d_ws, size_t ws_size,
                              hipStream_t stream) {
  const float* x   = (const float*)d_in[0];  // (1,B,N,HID)
  // d_in[1] res_feature, d_in[2] node_fea_for_res: unused (softmax shift invariance)
  const float* nfh = (const float*)d_in[3];  // (HID,1)
  const float* W   = (const float*)d_in[4];  // (HID,C)
  float* out = (float*)d_out;

  fused_attn_fill<<<B * C, 256, 0, stream>>>(x, nfh, W, out);
}